// Round 1
// baseline (377.672 us; speedup 1.0000x reference)
//
#include <hip/hip_runtime.h>
#include <math.h>

typedef _Float16 f16;
typedef _Float16 half8 __attribute__((ext_vector_type(8)));
typedef float f32x16 __attribute__((ext_vector_type(16)));

#define DEV __device__ __forceinline__

// ---------------- workspace layout (bytes) ----------------
#define W1F_OFF 0        // [L][nt2]      : 16 frags  = 16 KB
#define W2F_OFF 16384    // [L][kt4][nt2] : 64 frags  = 64 KB
#define WOF_OFF 81920    // [L][u8][kt4]  : 256 frags = 256 KB (used cols, 32-padded)
#define BOF_OFF 344064   // [L][u8][32] fp32 bias for used cols = 8 KB
#define SUMLOG_OFF 352256 // 1 fp32: sum over all layers/features of log|scale|

// ---------------- LDS: per-wave arena (7424 B), phases aliased -------------
// Each wave owns 32 samples and touches ONLY its own arena. DS ops execute
// in program order per wave, so the H staging buffer and the P slots may
// alias: every write of a phase follows the last read of the previous phase
// (same single-slot-pipeline argument as the p-slot reuse below).
//   H : [32][144] bytes f16 staging for h1/h2          (4608 B)
//   P : 2 slots x [32][116] bytes f32 spline params    (7424 B)
#define H_STRIDE  144
#define P_STRIDE  116
#define P_SLOT    3712     // 32 * 116
#define ARENA     7424     // = 2 * P_SLOT >= 4608
#define LDS_BYTES (4 * ARENA)   // 29696 B -> 4 blocks/CU (was 78848 -> 2)

DEV float frcp(float x){ return __builtin_amdgcn_rcpf(x); }
DEV float fexp(float x){ return __expf(x); }
DEV float flog(float x){ return __logf(x); }

// tanh = 1 - 2/(e^{2x}+1). Robust without clamp: x→+inf: rcp(inf)=0 → 1;
// x→-inf: rcp(1)=1 → -1. 5 instructions.
DEV float ftanh(float x){
  float e = fexp(2.f * x);
  float r = frcp(e + 1.f);
  return fmaf(-2.f, r, 1.f);
}

// Rational-quadratic spline forward + log-det (fp32, per-thread).
// Select chains reuse the bin compare bits b[j] (monotone, so
// (idx >= j) == b[j]) — the 7 compares are computed exactly once.
DEV void rq_spline(const float p[25], float xv, float &y_out, float &ld_out)
{
  float ew[8]; float sw = 0.f;
#pragma unroll
  for (int k = 0; k < 8; ++k){ ew[k] = fexp(p[k]); sw += ew[k]; }
  float rw = frcp(sw) * 19.9992f;           // (RMAX-RMIN) - K*MIN_BIN

  float xpos[9];
  xpos[0] = -10.f;
#pragma unroll
  for (int k = 0; k < 8; ++k) xpos[k + 1] = xpos[k] + fmaf(ew[k], rw, 1e-4f);

  bool b[8];
  int idx = 0;
#pragma unroll
  for (int j = 1; j < 8; ++j){ b[j] = (xv >= xpos[j]); idx += b[j] ? 1 : 0; }

  float xk = xpos[0], ewk = ew[0];
#pragma unroll
  for (int j = 1; j < 8; ++j){
    xk  = b[j] ? xpos[j] : xk;
    ewk = b[j] ? ew[j]   : ewk;
  }
  float bw = fmaf(ewk, rw, 1e-4f);

  float eh[8]; float shs = 0.f;
#pragma unroll
  for (int k = 0; k < 8; ++k){ eh[k] = fexp(p[8 + k]); shs += eh[k]; }
  float rh = frcp(shs) * 19.9992f;

  float S = 0.f, ehk = eh[0];
#pragma unroll
  for (int k = 1; k < 8; ++k){
    S   += b[k] ? eh[k - 1] : 0.f;
    ehk  = b[k] ? eh[k]     : ehk;
  }
  float yk = fmaf(S, rh, fmaf((float)idx, 1e-4f, -10.f));
  float bh = fmaf(ehk, rh, 1e-4f);

  float uA = p[16], uB = p[17];
#pragma unroll
  for (int j = 1; j < 8; ++j){
    uA = b[j] ? p[16 + j] : uA;
    uB = b[j] ? p[17 + j] : uB;
  }
  float vA = uA + 0.54116666f;
  float dk  = fmaxf(vA, 0.f) + flog(1.f + fexp(-fabsf(vA))) + 1e-4f;
  float vB = uB + 0.54116666f;
  float dk1 = fmaxf(vB, 0.f) + flog(1.f + fexp(-fabsf(vB))) + 1e-4f;

  float rbw = frcp(bw);
  float s   = bh * rbw;
  float zf  = fminf(fmaxf((xv - xk) * rbw, 0.f), 1.f);
  float z1  = 1.f - zf;
  float zz  = zf * zf, z01 = zf * z1;
  float den = s + (dk1 + dk - 2.f * s) * z01;
  float rden = frcp(den);
  float yv  = yk + bh * (s * zz + dk * z01) * rden;
  float num = dk1 * zz + 2.f * s * z01 + dk * z1 * z1;
  float ldv = flog(s * s * num * rden * rden);

  bool outside = (xv <= -10.f) || (xv >= 10.f);
  y_out  = outside ? xv : yv;
  ld_out = outside ? 0.f : ldv;
}

// ---------------- prep kernel: pack fp16 B-fragments into ws ----------------
// (unchanged — fragment formats identical)
extern "C" __global__ void __launch_bounds__(256)
prep_kernel(const float* __restrict__ W1, const float* __restrict__ W2,
            const float* __restrict__ Wo, const float* __restrict__ bout,
            const float* __restrict__ scale, char* __restrict__ ws)
{
  int tid = blockIdx.x * 256 + threadIdx.x;
  if (tid < 1024){                       // W1 frags: [L][nt2]
    int fi = tid >> 6, lane = tid & 63;
    int l = fi >> 1, nt = fi & 1;
    int n = nt * 32 + (lane & 31), khi = lane >> 5;
    half8 h;
#pragma unroll
    for (int j = 0; j < 8; ++j){ int k = khi * 8 + j; h[j] = (f16)W1[l * 1024 + k * 64 + n]; }
    *(half8*)(ws + W1F_OFF + fi * 1024 + lane * 16) = h;
  } else if (tid < 5120){                // W2 frags: [L][kt4][nt2]
    int idx = tid - 1024;
    int fi = idx >> 6, lane = idx & 63;
    int l = fi >> 3, kt = (fi >> 1) & 3, nt = fi & 1;
    int n = nt * 32 + (lane & 31), khi = lane >> 5;
    half8 h;
#pragma unroll
    for (int j = 0; j < 8; ++j){ int k = kt * 16 + khi * 8 + j; h[j] = (f16)W2[l * 4096 + k * 64 + n]; }
    *(half8*)(ws + W2F_OFF + fi * 1024 + lane * 16) = h;
  } else if (tid < 21504){               // Wout used-col frags: [L][u8][kt4]
    int idx = tid - 5120;
    int fi = idx >> 6, lane = idx & 63;
    int l = fi >> 5, u = (fi >> 2) & 7, kt = fi & 3;
    int f = (l & 1) + 2 * u;
    int c = lane & 31, khi = lane >> 5;
    half8 h;
#pragma unroll
    for (int j = 0; j < 8; ++j){
      int k = kt * 16 + khi * 8 + j;
      float v = (c < 25) ? Wo[l * 25600 + k * 400 + f * 25 + c] : 0.f;
      h[j] = (f16)v;
    }
    *(half8*)(ws + WOF_OFF + fi * 1024 + lane * 16) = h;
  } else if (tid < 23552){               // bout used cols: [L][u8][32] fp32
    int idx = tid - 21504;
    int l = idx >> 8, u = (idx >> 5) & 7, c = idx & 31;
    int f = (l & 1) + 2 * u;
    float v = (c < 25) ? bout[l * 400 + f * 25 + c] : 0.f;
    ((float*)(ws + BOF_OFF))[idx] = v;
  } else if (tid == 23552){              // sum of log|scale| over all layers
    float acc = 0.f;
    for (int i = 0; i < 128; ++i) acc += logf(fabsf(scale[i]));
    *(float*)(ws + SUMLOG_OFF) = acc;
  }
}

// ---------------- one coupling layer: 32 samples/wave, 2 lanes/sample ------
// Lane (ln31, khi) pairs with (ln31, khi^1) on sample wv*32+ln31.
// khi selects: the k-half of the A-fragments it computes/loads, the C-row
// quadrant it stores, and which 4 spline features (u = khi*4 + v) it owns.
template<int PAR>
DEV void layer_mfma(int l,
                    const float* __restrict__ W0, const float* __restrict__ b0,
                    const float* __restrict__ b1v, const float* __restrict__ b2v,
                    const float* __restrict__ scv, const float* __restrict__ shv,
                    const char* __restrict__ ws, char* lds,
                    float (&z)[16], float &logdet,
                    int lane, int ln31, int khi)
{
  const float* w0  = W0 + l * 256;
  const float* bb0 = b0 + l * 16;
  const int rowbase = khi * 4;     // C/D layout: row = (i&3)+8*(i>>2)+4*(lane>>5)

  // ---- hoisted weight-fragment loads (latency hidden behind h0 VALU) ----
  const half8* W1F = (const half8*)(ws + W1F_OFF);
  const half8* W2F = (const half8*)(ws + W2F_OFF);
  half8 w1f[2];
#pragma unroll
  for (int nt = 0; nt < 2; ++nt) w1f[nt] = W1F[(l * 2 + nt) * 64 + lane];
  half8 w2f[8];
#pragma unroll
  for (int kt = 0; kt < 4; ++kt)
#pragma unroll
    for (int nt = 0; nt < 2; ++nt)
      w2f[kt * 2 + nt] = W2F[((l * 4 + kt) * 2 + nt) * 64 + lane];
  float bias1[2], bias2[2];
#pragma unroll
  for (int nt = 0; nt < 2; ++nt){
    bias1[nt] = b1v[l * 64 + nt * 32 + ln31];
    bias2[nt] = b2v[l * 64 + nt * 32 + ln31];
  }

  // ---- h0 = tanh(mz @ W0 + b0): each lane computes only its own k-half,
  //      which IS its 32x32x16 A-fragment — no LDS round trip. ----
  const int j0 = khi * 8;
  float h0[8];
#pragma unroll
  for (int j = 0; j < 8; ++j) h0[j] = bb0[j0 + j];
#pragma unroll
  for (int u = 0; u < 8; ++u){
    const int f = (1 - PAR) + 2 * u;
    const float v = z[f];
#pragma unroll
    for (int j = 0; j < 8; ++j) h0[j] = fmaf(v, w0[f * 16 + j0 + j], h0[j]);
  }
  half8 a0;
#pragma unroll
  for (int j = 0; j < 8; ++j) a0[j] = (f16)ftanh(h0[j]);

  // ---- W1: h1 = tanh(h0 @ W1 + b1) via MFMA (bias folded into acc init) ----
  f32x16 d1[2];
#pragma unroll
  for (int nt = 0; nt < 2; ++nt)
#pragma unroll
    for (int i = 0; i < 16; ++i) d1[nt][i] = bias1[nt];
#pragma unroll
  for (int nt = 0; nt < 2; ++nt)
    d1[nt] = __builtin_amdgcn_mfma_f32_32x32x16_f16(a0, w1f[nt], d1[nt], 0, 0, 0);
#pragma unroll
  for (int nt = 0; nt < 2; ++nt)
#pragma unroll
    for (int i = 0; i < 16; ++i){
      int row = (i & 3) + 8 * (i >> 2) + rowbase;
      float v = ftanh(d1[nt][i]);
      *(f16*)(lds + row * H_STRIDE + (nt * 32 + ln31) * 2) = (f16)v;
    }

  // ---- W2: h2 = h1 @ W2 + b2 via MFMA (bias folded) ----
  half8 a1[4];
#pragma unroll
  for (int kt = 0; kt < 4; ++kt)
    a1[kt] = *(const half8*)(lds + ln31 * H_STRIDE + kt * 32 + khi * 16);
  f32x16 d2[2];
#pragma unroll
  for (int nt = 0; nt < 2; ++nt)
#pragma unroll
    for (int i = 0; i < 16; ++i) d2[nt][i] = bias2[nt];
#pragma unroll
  for (int kt = 0; kt < 4; ++kt)
#pragma unroll
    for (int nt = 0; nt < 2; ++nt)
      d2[nt] = __builtin_amdgcn_mfma_f32_32x32x16_f16(a1[kt], w2f[kt * 2 + nt], d2[nt], 0, 0, 0);

  // ---- prefetch v=0's Wout frags, both feature halves (hidden behind epi) --
  const half8* WOF = (const half8*)(ws + WOF_OFF);
  const float* BOF = (const float*)(ws + BOF_OFF);
  half8 bfn[2][4]; float biasn[2];
#pragma unroll
  for (int h = 0; h < 2; ++h){
    const int u = h * 4;
#pragma unroll
    for (int kt = 0; kt < 4; ++kt) bfn[h][kt] = WOF[((l * 8 + u) * 4 + kt) * 64 + lane];
    biasn[h] = BOF[(l * 8 + u) * 32 + ln31];
  }

#pragma unroll
  for (int nt = 0; nt < 2; ++nt)
#pragma unroll
    for (int i = 0; i < 16; ++i){
      int row = (i & 3) + 8 * (i >> 2) + rowbase;
      *(f16*)(lds + row * H_STRIDE + (nt * 32 + ln31) * 2) = (f16)d2[nt][i];
    }

  // ---- h2 A-fragments (reused across all feature iterations) ----
  half8 a2[4];
#pragma unroll
  for (int kt = 0; kt < 4; ++kt)
    a2[kt] = *(const half8*)(lds + ln31 * H_STRIDE + kt * 32 + khi * 16);

  // ---- feature-pair software pipeline ----
  // Iteration v computes features u=v (slot 0) and u=v+4 (slot 1) so all 64
  // lanes spline every iteration (lane half khi reads slot khi). p_{v+1}
  // MFMA + store issued BEFORE spline(v); per-wave DS program order makes
  // the single slot-pair safe (reads of p_v precede stores of p_{v+1}).
#pragma unroll
  for (int h = 0; h < 2; ++h){
    f32x16 dp;
#pragma unroll
    for (int i = 0; i < 16; ++i) dp[i] = biasn[h];
#pragma unroll
    for (int kt = 0; kt < 4; ++kt)
      dp = __builtin_amdgcn_mfma_f32_32x32x16_f16(a2[kt], bfn[h][kt], dp, 0, 0, 0);
    if (ln31 < 25){
#pragma unroll
      for (int i = 0; i < 16; ++i){
        int row = (i & 3) + 8 * (i >> 2) + rowbase;
        *(float*)(lds + h * P_SLOT + row * P_STRIDE + ln31 * 4) = dp[i];
      }
    }
  }
#pragma unroll
  for (int h = 0; h < 2; ++h){
    const int u = h * 4 + 1;
#pragma unroll
    for (int kt = 0; kt < 4; ++kt) bfn[h][kt] = WOF[((l * 8 + u) * 4 + kt) * 64 + lane];
    biasn[h] = BOF[(l * 8 + u) * 32 + ln31];
  }

#pragma unroll 1
  for (int v = 0; v < 4; ++v){
    // read own sample's p for this lane's feature (slot = khi)
    float p[25];
#pragma unroll
    for (int j = 0; j < 25; ++j)
      p[j] = *(const float*)(lds + khi * P_SLOT + ln31 * P_STRIDE + j * 4);

    // issue next iteration's MFMAs + stores before the spline
    if (v < 3){
#pragma unroll
      for (int h = 0; h < 2; ++h){
        f32x16 dp;
#pragma unroll
        for (int i = 0; i < 16; ++i) dp[i] = biasn[h];
#pragma unroll
        for (int kt = 0; kt < 4; ++kt)
          dp = __builtin_amdgcn_mfma_f32_32x32x16_f16(a2[kt], bfn[h][kt], dp, 0, 0, 0);
        if (ln31 < 25){
#pragma unroll
          for (int i = 0; i < 16; ++i){
            int row = (i & 3) + 8 * (i >> 2) + rowbase;
            *(float*)(lds + h * P_SLOT + row * P_STRIDE + ln31 * 4) = dp[i];
          }
        }
      }
      if (v < 2){
#pragma unroll
        for (int h = 0; h < 2; ++h){
          const int u = h * 4 + v + 2;
#pragma unroll
          for (int kt = 0; kt < 4; ++kt) bfn[h][kt] = WOF[((l * 8 + u) * 4 + kt) * 64 + lane];
          biasn[h] = BOF[(l * 8 + u) * 32 + ln31];
        }
      }
    }

    const int f0 = PAR + 2 * v;       // khi=0 lane's feature
    const int f1 = f0 + 8;            // khi=1 lane's feature (u = v+4)
    float xv = khi ? z[f1] : z[f0];
    float y, ld;
    rq_spline(p, xv, y, ld);
    float yx = __shfl_xor(y, 32, 64); // partner lane's updated feature
    z[f0] = khi ? yx : y;
    z[f1] = khi ? y  : yx;
    logdet += ld;
  }

  // ---- affine (log|scale| sum precomputed in prep) ----
  const float* scp = scv + l * 16;
  const float* shp = shv + l * 16;
#pragma unroll
  for (int j = 0; j < 16; ++j)
    z[j] = fmaf(z[j], scp[j], shp[j]);
}

extern "C" __global__ void __launch_bounds__(256, 4)
flow_kernel(const float* __restrict__ x,
            const float* __restrict__ W0, const float* __restrict__ b0,
            const float* __restrict__ b1v, const float* __restrict__ b2v,
            const float* __restrict__ scv, const float* __restrict__ shv,
            const char* __restrict__ ws, float* __restrict__ out, int B)
{
  extern __shared__ char lds_raw[];
  const int t    = threadIdx.x;
  const int lane = t & 63;
  const int wv   = t >> 6;
  const int ln31 = lane & 31;
  const int khi  = lane >> 5;
  char* lds = lds_raw + wv * ARENA;          // wave-private arena
  const int g = blockIdx.x * 128 + wv * 32 + ln31;  // both khi halves: same sample

  float z[16];
  const float4* xv4 = reinterpret_cast<const float4*>(x + (size_t)g * 16);
  float4 a0 = xv4[0], a1 = xv4[1], a2 = xv4[2], a3 = xv4[3];
  z[0]=a0.x; z[1]=a0.y; z[2]=a0.z; z[3]=a0.w;
  z[4]=a1.x; z[5]=a1.y; z[6]=a1.z; z[7]=a1.w;
  z[8]=a2.x; z[9]=a2.y; z[10]=a2.z; z[11]=a2.w;
  z[12]=a3.x; z[13]=a3.y; z[14]=a3.z; z[15]=a3.w;

  float logdet = 0.f;                        // per-lane partial (own features)
  for (int l = 7; l >= 0; --l){
    if (l & 1) layer_mfma<1>(l, W0, b0, b1v, b2v, scv, shv, ws, lds, z, logdet, lane, ln31, khi);
    else       layer_mfma<0>(l, W0, b0, b1v, b2v, scv, shv, ws, lds, z, logdet, lane, ln31, khi);
  }

  logdet += __shfl_xor(logdet, 32, 64);      // merge partner's feature partials

  float sumlog = *(const float*)(ws + SUMLOG_OFF);
  float ss = 0.f;
#pragma unroll
  for (int j = 0; j < 16; ++j) ss = fmaf(z[j], z[j], ss);
  if (khi == 0)
    out[g] = -0.5f * ss - 14.7030165f + logdet + sumlog;
}

extern "C" void kernel_launch(void* const* d_in, const int* in_sizes, int n_in,
                              void* d_out, int out_size, void* d_ws, size_t ws_size,
                              hipStream_t stream)
{
  const float* x    = (const float*)d_in[0];
  const float* W0   = (const float*)d_in[1];
  const float* b0   = (const float*)d_in[2];
  const float* W1   = (const float*)d_in[3];
  const float* b1   = (const float*)d_in[4];
  const float* W2   = (const float*)d_in[5];
  const float* b2   = (const float*)d_in[6];
  const float* Wout = (const float*)d_in[7];
  const float* bout = (const float*)d_in[8];
  const float* scale= (const float*)d_in[9];
  const float* shift= (const float*)d_in[10];

  int B = in_sizes[0] / 16;

  hipLaunchKernelGGL(prep_kernel, dim3(93), dim3(256), 0, stream,
                     W1, W2, Wout, bout, scale, (char*)d_ws);

  hipLaunchKernelGGL(flow_kernel, dim3(B / 128), dim3(256), LDS_BYTES, stream,
                     x, W0, b0, b1, b2, scale, shift,
                     (const char*)d_ws, (float*)d_out, B);
}

// Round 2
// 287.403 us; speedup vs baseline: 1.3141x; 1.3141x over previous
//
#include <hip/hip_runtime.h>
#include <math.h>

typedef _Float16 f16;
typedef _Float16 half8 __attribute__((ext_vector_type(8)));
typedef float f32x16 __attribute__((ext_vector_type(16)));

#define DEV __device__ __forceinline__

// ---------------- workspace layout (bytes) ----------------
#define W1F_OFF 0        // [L][nt2]      : 16 frags  = 16 KB
#define W2F_OFF 16384    // [L][kt4][nt2] : 64 frags  = 64 KB
#define WOF_OFF 81920    // [L][u8][kt4]  : 256 frags = 256 KB (used cols, 32-padded)
#define BOF_OFF 344064   // [L][u8][32] fp32 bias for used cols = 8 KB
#define SUMLOG_OFF 352256 // 1 fp32: sum over all layers/features of log|scale|

// ---------------- LDS: per-wave arena (7424 B), phases aliased -------------
// Each wave owns 32 samples and touches ONLY its own arena. DS ops execute
// in program order per wave, so the H staging buffer and the P slots may
// alias: every write of a phase follows the last read of the previous phase.
//   H : [32][144] bytes f16 staging for h1/h2          (4608 B)
//   P : 2 slots x [32][116] bytes f32 spline params    (7424 B)
#define H_STRIDE  144
#define P_STRIDE  116
#define P_SLOT    3712     // 32 * 116
#define ARENA     7424     // = 2 * P_SLOT >= 4608
#define LDS_BYTES (4 * ARENA)   // 29696 B -> 4 blocks/CU

DEV float frcp(float x){ return __builtin_amdgcn_rcpf(x); }
DEV float fexp(float x){ return __expf(x); }
DEV float flog(float x){ return __logf(x); }

// tanh = 1 - 2/(e^{2x}+1). Robust without clamp.
DEV float ftanh(float x){
  float e = fexp(2.f * x);
  float r = frcp(e + 1.f);
  return fmaf(-2.f, r, 1.f);
}

// Rational-quadratic spline forward + log-det (fp32, per-thread).
DEV void rq_spline(const float p[25], float xv, float &y_out, float &ld_out)
{
  float ew[8]; float sw = 0.f;
#pragma unroll
  for (int k = 0; k < 8; ++k){ ew[k] = fexp(p[k]); sw += ew[k]; }
  float rw = frcp(sw) * 19.9992f;           // (RMAX-RMIN) - K*MIN_BIN

  float xpos[9];
  xpos[0] = -10.f;
#pragma unroll
  for (int k = 0; k < 8; ++k) xpos[k + 1] = xpos[k] + fmaf(ew[k], rw, 1e-4f);

  bool b[8];
  int idx = 0;
#pragma unroll
  for (int j = 1; j < 8; ++j){ b[j] = (xv >= xpos[j]); idx += b[j] ? 1 : 0; }

  float xk = xpos[0], ewk = ew[0];
#pragma unroll
  for (int j = 1; j < 8; ++j){
    xk  = b[j] ? xpos[j] : xk;
    ewk = b[j] ? ew[j]   : ewk;
  }
  float bw = fmaf(ewk, rw, 1e-4f);

  float eh[8]; float shs = 0.f;
#pragma unroll
  for (int k = 0; k < 8; ++k){ eh[k] = fexp(p[8 + k]); shs += eh[k]; }
  float rh = frcp(shs) * 19.9992f;

  float S = 0.f, ehk = eh[0];
#pragma unroll
  for (int k = 1; k < 8; ++k){
    S   += b[k] ? eh[k - 1] : 0.f;
    ehk  = b[k] ? eh[k]     : ehk;
  }
  float yk = fmaf(S, rh, fmaf((float)idx, 1e-4f, -10.f));
  float bh = fmaf(ehk, rh, 1e-4f);

  float uA = p[16], uB = p[17];
#pragma unroll
  for (int j = 1; j < 8; ++j){
    uA = b[j] ? p[16 + j] : uA;
    uB = b[j] ? p[17 + j] : uB;
  }
  float vA = uA + 0.54116666f;
  float dk  = fmaxf(vA, 0.f) + flog(1.f + fexp(-fabsf(vA))) + 1e-4f;
  float vB = uB + 0.54116666f;
  float dk1 = fmaxf(vB, 0.f) + flog(1.f + fexp(-fabsf(vB))) + 1e-4f;

  float rbw = frcp(bw);
  float s   = bh * rbw;
  float zf  = fminf(fmaxf((xv - xk) * rbw, 0.f), 1.f);
  float z1  = 1.f - zf;
  float zz  = zf * zf, z01 = zf * z1;
  float den = s + (dk1 + dk - 2.f * s) * z01;
  float rden = frcp(den);
  float yv  = yk + bh * (s * zz + dk * z01) * rden;
  float num = dk1 * zz + 2.f * s * z01 + dk * z1 * z1;
  float ldv = flog(s * s * num * rden * rden);

  bool outside = (xv <= -10.f) || (xv >= 10.f);
  y_out  = outside ? xv : yv;
  ld_out = outside ? 0.f : ldv;
}

// ---------------- prep kernel: pack fp16 B-fragments into ws ----------------
extern "C" __global__ void __launch_bounds__(256)
prep_kernel(const float* __restrict__ W1, const float* __restrict__ W2,
            const float* __restrict__ Wo, const float* __restrict__ bout,
            const float* __restrict__ scale, char* __restrict__ ws)
{
  int tid = blockIdx.x * 256 + threadIdx.x;
  if (tid < 1024){                       // W1 frags: [L][nt2]
    int fi = tid >> 6, lane = tid & 63;
    int l = fi >> 1, nt = fi & 1;
    int n = nt * 32 + (lane & 31), khi = lane >> 5;
    half8 h;
#pragma unroll
    for (int j = 0; j < 8; ++j){ int k = khi * 8 + j; h[j] = (f16)W1[l * 1024 + k * 64 + n]; }
    *(half8*)(ws + W1F_OFF + fi * 1024 + lane * 16) = h;
  } else if (tid < 5120){                // W2 frags: [L][kt4][nt2]
    int idx = tid - 1024;
    int fi = idx >> 6, lane = idx & 63;
    int l = fi >> 3, kt = (fi >> 1) & 3, nt = fi & 1;
    int n = nt * 32 + (lane & 31), khi = lane >> 5;
    half8 h;
#pragma unroll
    for (int j = 0; j < 8; ++j){ int k = kt * 16 + khi * 8 + j; h[j] = (f16)W2[l * 4096 + k * 64 + n]; }
    *(half8*)(ws + W2F_OFF + fi * 1024 + lane * 16) = h;
  } else if (tid < 21504){               // Wout used-col frags: [L][u8][kt4]
    int idx = tid - 5120;
    int fi = idx >> 6, lane = idx & 63;
    int l = fi >> 5, u = (fi >> 2) & 7, kt = fi & 3;
    int f = (l & 1) + 2 * u;
    int c = lane & 31, khi = lane >> 5;
    half8 h;
#pragma unroll
    for (int j = 0; j < 8; ++j){
      int k = kt * 16 + khi * 8 + j;
      float v = (c < 25) ? Wo[l * 25600 + k * 400 + f * 25 + c] : 0.f;
      h[j] = (f16)v;
    }
    *(half8*)(ws + WOF_OFF + fi * 1024 + lane * 16) = h;
  } else if (tid < 23552){               // bout used cols: [L][u8][32] fp32
    int idx = tid - 21504;
    int l = idx >> 8, u = (idx >> 5) & 7, c = idx & 31;
    int f = (l & 1) + 2 * u;
    float v = (c < 25) ? bout[l * 400 + f * 25 + c] : 0.f;
    ((float*)(ws + BOF_OFF))[idx] = v;
  } else if (tid == 23552){              // sum of log|scale| over all layers
    float acc = 0.f;
    for (int i = 0; i < 128; ++i) acc += logf(fabsf(scale[i]));
    *(float*)(ws + SUMLOG_OFF) = acc;
  }
}

// ---------------- one coupling layer: 32 samples/wave, 2 lanes/sample ------
// Lane (ln31, khi) pairs with (ln31, khi^1) on sample wv*32+ln31.
// khi selects: the k-half of the A-fragments it computes/loads, the C-row
// quadrant it stores, and which 4 spline features (u = khi*4 + v) it owns.
//
// NOTE: the feature loop below is FULLY UNROLLED so that every index into
// z[16] is a compile-time constant. With `#pragma unroll 1` the dynamic
// z[f0]/z[f1] read+writes demoted z to scratch (rule #20): 940 MB of
// spill traffic per dispatch, 2x regression. Do not re-roll this loop.
template<int PAR>
DEV void layer_mfma(int l,
                    const float* __restrict__ W0, const float* __restrict__ b0,
                    const float* __restrict__ b1v, const float* __restrict__ b2v,
                    const float* __restrict__ scv, const float* __restrict__ shv,
                    const char* __restrict__ ws, char* lds,
                    float (&z)[16], float &logdet,
                    int lane, int ln31, int khi)
{
  const float* w0  = W0 + l * 256;
  const float* bb0 = b0 + l * 16;
  const int rowbase = khi * 4;     // C/D layout: row = (i&3)+8*(i>>2)+4*(lane>>5)

  // ---- hoisted weight-fragment loads (latency hidden behind h0 VALU) ----
  const half8* W1F = (const half8*)(ws + W1F_OFF);
  const half8* W2F = (const half8*)(ws + W2F_OFF);
  half8 w1f[2];
#pragma unroll
  for (int nt = 0; nt < 2; ++nt) w1f[nt] = W1F[(l * 2 + nt) * 64 + lane];
  half8 w2f[8];
#pragma unroll
  for (int kt = 0; kt < 4; ++kt)
#pragma unroll
    for (int nt = 0; nt < 2; ++nt)
      w2f[kt * 2 + nt] = W2F[((l * 4 + kt) * 2 + nt) * 64 + lane];
  float bias1[2], bias2[2];
#pragma unroll
  for (int nt = 0; nt < 2; ++nt){
    bias1[nt] = b1v[l * 64 + nt * 32 + ln31];
    bias2[nt] = b2v[l * 64 + nt * 32 + ln31];
  }

  // ---- h0 = tanh(mz @ W0 + b0): each lane computes only its own k-half,
  //      which IS its 32x32x16 A-fragment — no LDS round trip. ----
  const int j0 = khi * 8;
  float h0[8];
#pragma unroll
  for (int j = 0; j < 8; ++j) h0[j] = bb0[j0 + j];
#pragma unroll
  for (int u = 0; u < 8; ++u){
    const int f = (1 - PAR) + 2 * u;
    const float v = z[f];
#pragma unroll
    for (int j = 0; j < 8; ++j) h0[j] = fmaf(v, w0[f * 16 + j0 + j], h0[j]);
  }
  half8 a0;
#pragma unroll
  for (int j = 0; j < 8; ++j) a0[j] = (f16)ftanh(h0[j]);

  // ---- W1: h1 = tanh(h0 @ W1 + b1) via MFMA (bias folded into acc init) ----
  f32x16 d1[2];
#pragma unroll
  for (int nt = 0; nt < 2; ++nt)
#pragma unroll
    for (int i = 0; i < 16; ++i) d1[nt][i] = bias1[nt];
#pragma unroll
  for (int nt = 0; nt < 2; ++nt)
    d1[nt] = __builtin_amdgcn_mfma_f32_32x32x16_f16(a0, w1f[nt], d1[nt], 0, 0, 0);
#pragma unroll
  for (int nt = 0; nt < 2; ++nt)
#pragma unroll
    for (int i = 0; i < 16; ++i){
      int row = (i & 3) + 8 * (i >> 2) + rowbase;
      float v = ftanh(d1[nt][i]);
      *(f16*)(lds + row * H_STRIDE + (nt * 32 + ln31) * 2) = (f16)v;
    }

  // ---- W2: h2 = h1 @ W2 + b2 via MFMA (bias folded) ----
  half8 a1[4];
#pragma unroll
  for (int kt = 0; kt < 4; ++kt)
    a1[kt] = *(const half8*)(lds + ln31 * H_STRIDE + kt * 32 + khi * 16);
  f32x16 d2[2];
#pragma unroll
  for (int nt = 0; nt < 2; ++nt)
#pragma unroll
    for (int i = 0; i < 16; ++i) d2[nt][i] = bias2[nt];
#pragma unroll
  for (int kt = 0; kt < 4; ++kt)
#pragma unroll
    for (int nt = 0; nt < 2; ++nt)
      d2[nt] = __builtin_amdgcn_mfma_f32_32x32x16_f16(a1[kt], w2f[kt * 2 + nt], d2[nt], 0, 0, 0);

  // ---- prefetch v=0's Wout frags, both feature halves (hidden behind epi) --
  const half8* WOF = (const half8*)(ws + WOF_OFF);
  const float* BOF = (const float*)(ws + BOF_OFF);
  half8 bfn[2][4]; float biasn[2];
#pragma unroll
  for (int h = 0; h < 2; ++h){
    const int u = h * 4;
#pragma unroll
    for (int kt = 0; kt < 4; ++kt) bfn[h][kt] = WOF[((l * 8 + u) * 4 + kt) * 64 + lane];
    biasn[h] = BOF[(l * 8 + u) * 32 + ln31];
  }

#pragma unroll
  for (int nt = 0; nt < 2; ++nt)
#pragma unroll
    for (int i = 0; i < 16; ++i){
      int row = (i & 3) + 8 * (i >> 2) + rowbase;
      *(f16*)(lds + row * H_STRIDE + (nt * 32 + ln31) * 2) = (f16)d2[nt][i];
    }

  // ---- h2 A-fragments (reused across all feature iterations) ----
  half8 a2[4];
#pragma unroll
  for (int kt = 0; kt < 4; ++kt)
    a2[kt] = *(const half8*)(lds + ln31 * H_STRIDE + kt * 32 + khi * 16);

  // ---- feature-pair software pipeline (FULLY UNROLLED — see note above) ----
  // Iteration v computes features u=v (slot 0) and u=v+4 (slot 1) so all 64
  // lanes spline every iteration (lane half khi reads slot khi). p_{v+1}
  // MFMA + store issued BEFORE spline(v); per-wave DS program order makes
  // the single slot-pair safe (reads of p_v precede stores of p_{v+1}).
#pragma unroll
  for (int h = 0; h < 2; ++h){
    f32x16 dp;
#pragma unroll
    for (int i = 0; i < 16; ++i) dp[i] = biasn[h];
#pragma unroll
    for (int kt = 0; kt < 4; ++kt)
      dp = __builtin_amdgcn_mfma_f32_32x32x16_f16(a2[kt], bfn[h][kt], dp, 0, 0, 0);
    if (ln31 < 25){
#pragma unroll
      for (int i = 0; i < 16; ++i){
        int row = (i & 3) + 8 * (i >> 2) + rowbase;
        *(float*)(lds + h * P_SLOT + row * P_STRIDE + ln31 * 4) = dp[i];
      }
    }
  }
#pragma unroll
  for (int h = 0; h < 2; ++h){
    const int u = h * 4 + 1;
#pragma unroll
    for (int kt = 0; kt < 4; ++kt) bfn[h][kt] = WOF[((l * 8 + u) * 4 + kt) * 64 + lane];
    biasn[h] = BOF[(l * 8 + u) * 32 + ln31];
  }

#pragma unroll
  for (int v = 0; v < 4; ++v){
    // read own sample's p for this lane's feature (slot = khi)
    float p[25];
#pragma unroll
    for (int j = 0; j < 25; ++j)
      p[j] = *(const float*)(lds + khi * P_SLOT + ln31 * P_STRIDE + j * 4);

    // issue next iteration's MFMAs + stores before the spline
    if (v < 3){
#pragma unroll
      for (int h = 0; h < 2; ++h){
        f32x16 dp;
#pragma unroll
        for (int i = 0; i < 16; ++i) dp[i] = biasn[h];
#pragma unroll
        for (int kt = 0; kt < 4; ++kt)
          dp = __builtin_amdgcn_mfma_f32_32x32x16_f16(a2[kt], bfn[h][kt], dp, 0, 0, 0);
        if (ln31 < 25){
#pragma unroll
          for (int i = 0; i < 16; ++i){
            int row = (i & 3) + 8 * (i >> 2) + rowbase;
            *(float*)(lds + h * P_SLOT + row * P_STRIDE + ln31 * 4) = dp[i];
          }
        }
      }
      if (v < 2){
#pragma unroll
        for (int h = 0; h < 2; ++h){
          const int u = h * 4 + v + 2;
#pragma unroll
          for (int kt = 0; kt < 4; ++kt) bfn[h][kt] = WOF[((l * 8 + u) * 4 + kt) * 64 + lane];
          biasn[h] = BOF[(l * 8 + u) * 32 + ln31];
        }
      }
    }

    const int f0 = PAR + 2 * v;       // khi=0 lane's feature (compile-time)
    const int f1 = f0 + 8;            // khi=1 lane's feature (compile-time)
    float xv = khi ? z[f1] : z[f0];
    float y, ld;
    rq_spline(p, xv, y, ld);
    float yx = __shfl_xor(y, 32, 64); // partner lane's updated feature
    z[f0] = khi ? yx : y;
    z[f1] = khi ? y  : yx;
    logdet += ld;
  }

  // ---- affine (log|scale| sum precomputed in prep) ----
  const float* scp = scv + l * 16;
  const float* shp = shv + l * 16;
#pragma unroll
  for (int j = 0; j < 16; ++j)
    z[j] = fmaf(z[j], scp[j], shp[j]);
}

extern "C" __global__ void __launch_bounds__(256, 4)
flow_kernel(const float* __restrict__ x,
            const float* __restrict__ W0, const float* __restrict__ b0,
            const float* __restrict__ b1v, const float* __restrict__ b2v,
            const float* __restrict__ scv, const float* __restrict__ shv,
            const char* __restrict__ ws, float* __restrict__ out, int B)
{
  extern __shared__ char lds_raw[];
  const int t    = threadIdx.x;
  const int lane = t & 63;
  const int wv   = t >> 6;
  const int ln31 = lane & 31;
  const int khi  = lane >> 5;
  char* lds = lds_raw + wv * ARENA;          // wave-private arena
  const int g = blockIdx.x * 128 + wv * 32 + ln31;  // both khi halves: same sample

  float z[16];
  const float4* xv4 = reinterpret_cast<const float4*>(x + (size_t)g * 16);
  float4 a0 = xv4[0], a1 = xv4[1], a2 = xv4[2], a3 = xv4[3];
  z[0]=a0.x; z[1]=a0.y; z[2]=a0.z; z[3]=a0.w;
  z[4]=a1.x; z[5]=a1.y; z[6]=a1.z; z[7]=a1.w;
  z[8]=a2.x; z[9]=a2.y; z[10]=a2.z; z[11]=a2.w;
  z[12]=a3.x; z[13]=a3.y; z[14]=a3.z; z[15]=a3.w;

  float logdet = 0.f;                        // per-lane partial (own features)
  for (int l = 7; l >= 0; --l){
    if (l & 1) layer_mfma<1>(l, W0, b0, b1v, b2v, scv, shv, ws, lds, z, logdet, lane, ln31, khi);
    else       layer_mfma<0>(l, W0, b0, b1v, b2v, scv, shv, ws, lds, z, logdet, lane, ln31, khi);
  }

  logdet += __shfl_xor(logdet, 32, 64);      // merge partner's feature partials

  float sumlog = *(const float*)(ws + SUMLOG_OFF);
  float ss = 0.f;
#pragma unroll
  for (int j = 0; j < 16; ++j) ss = fmaf(z[j], z[j], ss);
  if (khi == 0)
    out[g] = -0.5f * ss - 14.7030165f + logdet + sumlog;
}

extern "C" void kernel_launch(void* const* d_in, const int* in_sizes, int n_in,
                              void* d_out, int out_size, void* d_ws, size_t ws_size,
                              hipStream_t stream)
{
  const float* x    = (const float*)d_in[0];
  const float* W0   = (const float*)d_in[1];
  const float* b0   = (const float*)d_in[2];
  const float* W1   = (const float*)d_in[3];
  const float* b1   = (const float*)d_in[4];
  const float* W2   = (const float*)d_in[5];
  const float* b2   = (const float*)d_in[6];
  const float* Wout = (const float*)d_in[7];
  const float* bout = (const float*)d_in[8];
  const float* scale= (const float*)d_in[9];
  const float* shift= (const float*)d_in[10];

  int B = in_sizes[0] / 16;

  hipLaunchKernelGGL(prep_kernel, dim3(93), dim3(256), 0, stream,
                     W1, W2, Wout, bout, scale, (char*)d_ws);

  hipLaunchKernelGGL(flow_kernel, dim3(B / 128), dim3(256), LDS_BYTES, stream,
                     x, W0, b0, b1, b2, scale, shift,
                     (const char*)d_ws, (float*)d_out, B);
}

// Round 3
// 219.163 us; speedup vs baseline: 1.7232x; 1.3114x over previous
//
#include <hip/hip_runtime.h>
#include <math.h>

typedef _Float16 f16;
typedef _Float16 half8 __attribute__((ext_vector_type(8)));
typedef float f32x16 __attribute__((ext_vector_type(16)));

#define DEV __device__ __forceinline__

// ---------------- workspace layout (bytes) ----------------
#define W1F_OFF 0        // [L][nt2]      : 16 frags  = 16 KB
#define W2F_OFF 16384    // [L][kt4][nt2] : 64 frags  = 64 KB
#define WOF_OFF 81920    // [L][u8][kt4]  : 256 frags = 256 KB (used cols, 32-padded)
#define BOF_OFF 344064   // [L][u8][32] fp32 bias for used cols = 8 KB
#define SUMLOG_OFF 352256 // 1 fp32: sum over all layers/features of log|scale|

// ---------------- LDS: per-wave arena (7424 B), phases aliased -------------
// Each wave owns 32 samples and touches ONLY its own arena. DS ops execute
// in program order per wave, so the H staging buffer and the P slots may
// alias: every write of a phase follows the last read of the previous phase.
//   H : [32][144] bytes f16 staging for h1/h2          (4608 B)
//   P : 2 slots x [32][116] bytes f32 spline params    (7424 B)
#define H_STRIDE  144
#define P_STRIDE  116
#define P_SLOT    3712     // 32 * 116
#define ARENA     7424     // = 2 * P_SLOT >= 4608
#define LDS_BYTES (4 * ARENA)   // 29696 B -> 4 blocks/CU possible

DEV float frcp(float x){ return __builtin_amdgcn_rcpf(x); }
DEV float fexp(float x){ return __expf(x); }
DEV float flog(float x){ return __logf(x); }

// tanh = 1 - 2/(e^{2x}+1). Robust without clamp.
DEV float ftanh(float x){
  float e = fexp(2.f * x);
  float r = frcp(e + 1.f);
  return fmaf(-2.f, r, 1.f);
}

// Rational-quadratic spline forward + log-det (fp32, per-thread).
DEV void rq_spline(const float p[25], float xv, float &y_out, float &ld_out)
{
  float ew[8]; float sw = 0.f;
#pragma unroll
  for (int k = 0; k < 8; ++k){ ew[k] = fexp(p[k]); sw += ew[k]; }
  float rw = frcp(sw) * 19.9992f;           // (RMAX-RMIN) - K*MIN_BIN

  float xpos[9];
  xpos[0] = -10.f;
#pragma unroll
  for (int k = 0; k < 8; ++k) xpos[k + 1] = xpos[k] + fmaf(ew[k], rw, 1e-4f);

  bool b[8];
  int idx = 0;
#pragma unroll
  for (int j = 1; j < 8; ++j){ b[j] = (xv >= xpos[j]); idx += b[j] ? 1 : 0; }

  float xk = xpos[0], ewk = ew[0];
#pragma unroll
  for (int j = 1; j < 8; ++j){
    xk  = b[j] ? xpos[j] : xk;
    ewk = b[j] ? ew[j]   : ewk;
  }
  float bw = fmaf(ewk, rw, 1e-4f);

  float eh[8]; float shs = 0.f;
#pragma unroll
  for (int k = 0; k < 8; ++k){ eh[k] = fexp(p[8 + k]); shs += eh[k]; }
  float rh = frcp(shs) * 19.9992f;

  float S = 0.f, ehk = eh[0];
#pragma unroll
  for (int k = 1; k < 8; ++k){
    S   += b[k] ? eh[k - 1] : 0.f;
    ehk  = b[k] ? eh[k]     : ehk;
  }
  float yk = fmaf(S, rh, fmaf((float)idx, 1e-4f, -10.f));
  float bh = fmaf(ehk, rh, 1e-4f);

  float uA = p[16], uB = p[17];
#pragma unroll
  for (int j = 1; j < 8; ++j){
    uA = b[j] ? p[16 + j] : uA;
    uB = b[j] ? p[17 + j] : uB;
  }
  float vA = uA + 0.54116666f;
  float dk  = fmaxf(vA, 0.f) + flog(1.f + fexp(-fabsf(vA))) + 1e-4f;
  float vB = uB + 0.54116666f;
  float dk1 = fmaxf(vB, 0.f) + flog(1.f + fexp(-fabsf(vB))) + 1e-4f;

  float rbw = frcp(bw);
  float s   = bh * rbw;
  float zf  = fminf(fmaxf((xv - xk) * rbw, 0.f), 1.f);
  float z1  = 1.f - zf;
  float zz  = zf * zf, z01 = zf * z1;
  float den = s + (dk1 + dk - 2.f * s) * z01;
  float rden = frcp(den);
  float yv  = yk + bh * (s * zz + dk * z01) * rden;
  float num = dk1 * zz + 2.f * s * z01 + dk * z1 * z1;
  float ldv = flog(s * s * num * rden * rden);

  bool outside = (xv <= -10.f) || (xv >= 10.f);
  y_out  = outside ? xv : yv;
  ld_out = outside ? 0.f : ldv;
}

// ---------------- prep kernel: pack fp16 B-fragments into ws ----------------
extern "C" __global__ void __launch_bounds__(256)
prep_kernel(const float* __restrict__ W1, const float* __restrict__ W2,
            const float* __restrict__ Wo, const float* __restrict__ bout,
            const float* __restrict__ scale, char* __restrict__ ws)
{
  int tid = blockIdx.x * 256 + threadIdx.x;
  if (tid < 1024){                       // W1 frags: [L][nt2]
    int fi = tid >> 6, lane = tid & 63;
    int l = fi >> 1, nt = fi & 1;
    int n = nt * 32 + (lane & 31), khi = lane >> 5;
    half8 h;
#pragma unroll
    for (int j = 0; j < 8; ++j){ int k = khi * 8 + j; h[j] = (f16)W1[l * 1024 + k * 64 + n]; }
    *(half8*)(ws + W1F_OFF + fi * 1024 + lane * 16) = h;
  } else if (tid < 5120){                // W2 frags: [L][kt4][nt2]
    int idx = tid - 1024;
    int fi = idx >> 6, lane = idx & 63;
    int l = fi >> 3, kt = (fi >> 1) & 3, nt = fi & 1;
    int n = nt * 32 + (lane & 31), khi = lane >> 5;
    half8 h;
#pragma unroll
    for (int j = 0; j < 8; ++j){ int k = kt * 16 + khi * 8 + j; h[j] = (f16)W2[l * 4096 + k * 64 + n]; }
    *(half8*)(ws + W2F_OFF + fi * 1024 + lane * 16) = h;
  } else if (tid < 21504){               // Wout used-col frags: [L][u8][kt4]
    int idx = tid - 5120;
    int fi = idx >> 6, lane = idx & 63;
    int l = fi >> 5, u = (fi >> 2) & 7, kt = fi & 3;
    int f = (l & 1) + 2 * u;
    int c = lane & 31, khi = lane >> 5;
    half8 h;
#pragma unroll
    for (int j = 0; j < 8; ++j){
      int k = kt * 16 + khi * 8 + j;
      float v = (c < 25) ? Wo[l * 25600 + k * 400 + f * 25 + c] : 0.f;
      h[j] = (f16)v;
    }
    *(half8*)(ws + WOF_OFF + fi * 1024 + lane * 16) = h;
  } else if (tid < 23552){               // bout used cols: [L][u8][32] fp32
    int idx = tid - 21504;
    int l = idx >> 8, u = (idx >> 5) & 7, c = idx & 31;
    int f = (l & 1) + 2 * u;
    float v = (c < 25) ? bout[l * 400 + f * 25 + c] : 0.f;
    ((float*)(ws + BOF_OFF))[idx] = v;
  } else if (tid == 23552){              // sum of log|scale| over all layers
    float acc = 0.f;
    for (int i = 0; i < 128; ++i) acc += logf(fabsf(scale[i]));
    *(float*)(ws + SUMLOG_OFF) = acc;
  }
}

// ---------------- one coupling layer: 32 samples/wave, 2 lanes/sample ------
// Lane (ln31, khi) pairs with (ln31, khi^1) on sample wv*32+ln31.
// khi selects: the k-half of the A-fragments it computes/loads, the C-row
// quadrant it stores, and which 4 spline features (u = khi*4 + v) it owns.
//
// NOTE 1: the feature loop below is FULLY UNROLLED so that every index into
// z[16] is a compile-time constant. With `#pragma unroll 1` the dynamic
// z[f0]/z[f1] read+writes demoted z to scratch (rule #20): 940 MB of
// spill traffic per dispatch, 2x regression. Do not re-roll this loop.
// NOTE 2: flow_kernel must be __launch_bounds__(256, 2). With (256, 4) the
// 128-VGPR cap forced the allocator to spill f32x16 blocks (505 MB scratch
// traffic, VGPR collapsed to 64, kernel became scratch-BW-bound at 227 us).
// This structure lives in ~104-130 VGPR uncapped; LDS already permits
// 4 blocks/CU, so no launch-bounds pressure hint is needed for occupancy.
template<int PAR>
DEV void layer_mfma(int l,
                    const float* __restrict__ W0, const float* __restrict__ b0,
                    const float* __restrict__ b1v, const float* __restrict__ b2v,
                    const float* __restrict__ scv, const float* __restrict__ shv,
                    const char* __restrict__ ws, char* lds,
                    float (&z)[16], float &logdet,
                    int lane, int ln31, int khi)
{
  const float* w0  = W0 + l * 256;
  const float* bb0 = b0 + l * 16;
  const int rowbase = khi * 4;     // C/D layout: row = (i&3)+8*(i>>2)+4*(lane>>5)

  // ---- hoisted weight-fragment loads (latency hidden behind h0 VALU) ----
  const half8* W1F = (const half8*)(ws + W1F_OFF);
  const half8* W2F = (const half8*)(ws + W2F_OFF);
  half8 w1f[2];
#pragma unroll
  for (int nt = 0; nt < 2; ++nt) w1f[nt] = W1F[(l * 2 + nt) * 64 + lane];
  half8 w2f[8];
#pragma unroll
  for (int kt = 0; kt < 4; ++kt)
#pragma unroll
    for (int nt = 0; nt < 2; ++nt)
      w2f[kt * 2 + nt] = W2F[((l * 4 + kt) * 2 + nt) * 64 + lane];
  float bias1[2], bias2[2];
#pragma unroll
  for (int nt = 0; nt < 2; ++nt){
    bias1[nt] = b1v[l * 64 + nt * 32 + ln31];
    bias2[nt] = b2v[l * 64 + nt * 32 + ln31];
  }

  // ---- h0 = tanh(mz @ W0 + b0): each lane computes only its own k-half,
  //      which IS its 32x32x16 A-fragment — no LDS round trip. ----
  const int j0 = khi * 8;
  float h0[8];
#pragma unroll
  for (int j = 0; j < 8; ++j) h0[j] = bb0[j0 + j];
#pragma unroll
  for (int u = 0; u < 8; ++u){
    const int f = (1 - PAR) + 2 * u;
    const float v = z[f];
#pragma unroll
    for (int j = 0; j < 8; ++j) h0[j] = fmaf(v, w0[f * 16 + j0 + j], h0[j]);
  }
  half8 a0;
#pragma unroll
  for (int j = 0; j < 8; ++j) a0[j] = (f16)ftanh(h0[j]);

  // ---- W1: h1 = tanh(h0 @ W1 + b1) via MFMA (bias folded into acc init) ----
  f32x16 d1[2];
#pragma unroll
  for (int nt = 0; nt < 2; ++nt)
#pragma unroll
    for (int i = 0; i < 16; ++i) d1[nt][i] = bias1[nt];
#pragma unroll
  for (int nt = 0; nt < 2; ++nt)
    d1[nt] = __builtin_amdgcn_mfma_f32_32x32x16_f16(a0, w1f[nt], d1[nt], 0, 0, 0);
#pragma unroll
  for (int nt = 0; nt < 2; ++nt)
#pragma unroll
    for (int i = 0; i < 16; ++i){
      int row = (i & 3) + 8 * (i >> 2) + rowbase;
      float v = ftanh(d1[nt][i]);
      *(f16*)(lds + row * H_STRIDE + (nt * 32 + ln31) * 2) = (f16)v;
    }

  // ---- W2: h2 = h1 @ W2 + b2 via MFMA (bias folded) ----
  half8 a1[4];
#pragma unroll
  for (int kt = 0; kt < 4; ++kt)
    a1[kt] = *(const half8*)(lds + ln31 * H_STRIDE + kt * 32 + khi * 16);
  f32x16 d2[2];
#pragma unroll
  for (int nt = 0; nt < 2; ++nt)
#pragma unroll
    for (int i = 0; i < 16; ++i) d2[nt][i] = bias2[nt];
#pragma unroll
  for (int kt = 0; kt < 4; ++kt)
#pragma unroll
    for (int nt = 0; nt < 2; ++nt)
      d2[nt] = __builtin_amdgcn_mfma_f32_32x32x16_f16(a1[kt], w2f[kt * 2 + nt], d2[nt], 0, 0, 0);

  // ---- prefetch v=0's Wout frags, both feature halves (hidden behind epi) --
  const half8* WOF = (const half8*)(ws + WOF_OFF);
  const float* BOF = (const float*)(ws + BOF_OFF);
  half8 bfn[2][4]; float biasn[2];
#pragma unroll
  for (int h = 0; h < 2; ++h){
    const int u = h * 4;
#pragma unroll
    for (int kt = 0; kt < 4; ++kt) bfn[h][kt] = WOF[((l * 8 + u) * 4 + kt) * 64 + lane];
    biasn[h] = BOF[(l * 8 + u) * 32 + ln31];
  }

#pragma unroll
  for (int nt = 0; nt < 2; ++nt)
#pragma unroll
    for (int i = 0; i < 16; ++i){
      int row = (i & 3) + 8 * (i >> 2) + rowbase;
      *(f16*)(lds + row * H_STRIDE + (nt * 32 + ln31) * 2) = (f16)d2[nt][i];
    }

  // ---- h2 A-fragments (reused across all feature iterations) ----
  half8 a2[4];
#pragma unroll
  for (int kt = 0; kt < 4; ++kt)
    a2[kt] = *(const half8*)(lds + ln31 * H_STRIDE + kt * 32 + khi * 16);

  // ---- feature-pair software pipeline (FULLY UNROLLED — see NOTE 1) ----
  // Iteration v computes features u=v (slot 0) and u=v+4 (slot 1) so all 64
  // lanes spline every iteration (lane half khi reads slot khi). p_{v+1}
  // MFMA + store issued BEFORE spline(v); per-wave DS program order makes
  // the single slot-pair safe (reads of p_v precede stores of p_{v+1}).
#pragma unroll
  for (int h = 0; h < 2; ++h){
    f32x16 dp;
#pragma unroll
    for (int i = 0; i < 16; ++i) dp[i] = biasn[h];
#pragma unroll
    for (int kt = 0; kt < 4; ++kt)
      dp = __builtin_amdgcn_mfma_f32_32x32x16_f16(a2[kt], bfn[h][kt], dp, 0, 0, 0);
    if (ln31 < 25){
#pragma unroll
      for (int i = 0; i < 16; ++i){
        int row = (i & 3) + 8 * (i >> 2) + rowbase;
        *(float*)(lds + h * P_SLOT + row * P_STRIDE + ln31 * 4) = dp[i];
      }
    }
  }
#pragma unroll
  for (int h = 0; h < 2; ++h){
    const int u = h * 4 + 1;
#pragma unroll
    for (int kt = 0; kt < 4; ++kt) bfn[h][kt] = WOF[((l * 8 + u) * 4 + kt) * 64 + lane];
    biasn[h] = BOF[(l * 8 + u) * 32 + ln31];
  }

#pragma unroll
  for (int v = 0; v < 4; ++v){
    // read own sample's p for this lane's feature (slot = khi)
    float p[25];
#pragma unroll
    for (int j = 0; j < 25; ++j)
      p[j] = *(const float*)(lds + khi * P_SLOT + ln31 * P_STRIDE + j * 4);

    // issue next iteration's MFMAs + stores before the spline
    if (v < 3){
#pragma unroll
      for (int h = 0; h < 2; ++h){
        f32x16 dp;
#pragma unroll
        for (int i = 0; i < 16; ++i) dp[i] = biasn[h];
#pragma unroll
        for (int kt = 0; kt < 4; ++kt)
          dp = __builtin_amdgcn_mfma_f32_32x32x16_f16(a2[kt], bfn[h][kt], dp, 0, 0, 0);
        if (ln31 < 25){
#pragma unroll
          for (int i = 0; i < 16; ++i){
            int row = (i & 3) + 8 * (i >> 2) + rowbase;
            *(float*)(lds + h * P_SLOT + row * P_STRIDE + ln31 * 4) = dp[i];
          }
        }
      }
      if (v < 2){
#pragma unroll
        for (int h = 0; h < 2; ++h){
          const int u = h * 4 + v + 2;
#pragma unroll
          for (int kt = 0; kt < 4; ++kt) bfn[h][kt] = WOF[((l * 8 + u) * 4 + kt) * 64 + lane];
          biasn[h] = BOF[(l * 8 + u) * 32 + ln31];
        }
      }
    }

    const int f0 = PAR + 2 * v;       // khi=0 lane's feature (compile-time)
    const int f1 = f0 + 8;            // khi=1 lane's feature (compile-time)
    float xv = khi ? z[f1] : z[f0];
    float y, ld;
    rq_spline(p, xv, y, ld);
    float yx = __shfl_xor(y, 32, 64); // partner lane's updated feature
    z[f0] = khi ? yx : y;
    z[f1] = khi ? y  : yx;
    logdet += ld;
  }

  // ---- affine (log|scale| sum precomputed in prep) ----
  const float* scp = scv + l * 16;
  const float* shp = shv + l * 16;
#pragma unroll
  for (int j = 0; j < 16; ++j)
    z[j] = fmaf(z[j], scp[j], shp[j]);
}

extern "C" __global__ void __launch_bounds__(256, 2)
flow_kernel(const float* __restrict__ x,
            const float* __restrict__ W0, const float* __restrict__ b0,
            const float* __restrict__ b1v, const float* __restrict__ b2v,
            const float* __restrict__ scv, const float* __restrict__ shv,
            const char* __restrict__ ws, float* __restrict__ out, int B)
{
  extern __shared__ char lds_raw[];
  const int t    = threadIdx.x;
  const int lane = t & 63;
  const int wv   = t >> 6;
  const int ln31 = lane & 31;
  const int khi  = lane >> 5;
  char* lds = lds_raw + wv * ARENA;          // wave-private arena
  const int g = blockIdx.x * 128 + wv * 32 + ln31;  // both khi halves: same sample

  float z[16];
  const float4* xv4 = reinterpret_cast<const float4*>(x + (size_t)g * 16);
  float4 a0 = xv4[0], a1 = xv4[1], a2 = xv4[2], a3 = xv4[3];
  z[0]=a0.x; z[1]=a0.y; z[2]=a0.z; z[3]=a0.w;
  z[4]=a1.x; z[5]=a1.y; z[6]=a1.z; z[7]=a1.w;
  z[8]=a2.x; z[9]=a2.y; z[10]=a2.z; z[11]=a2.w;
  z[12]=a3.x; z[13]=a3.y; z[14]=a3.z; z[15]=a3.w;

  float logdet = 0.f;                        // per-lane partial (own features)
  for (int l = 7; l >= 0; --l){
    if (l & 1) layer_mfma<1>(l, W0, b0, b1v, b2v, scv, shv, ws, lds, z, logdet, lane, ln31, khi);
    else       layer_mfma<0>(l, W0, b0, b1v, b2v, scv, shv, ws, lds, z, logdet, lane, ln31, khi);
  }

  logdet += __shfl_xor(logdet, 32, 64);      // merge partner's feature partials

  float sumlog = *(const float*)(ws + SUMLOG_OFF);
  float ss = 0.f;
#pragma unroll
  for (int j = 0; j < 16; ++j) ss = fmaf(z[j], z[j], ss);
  if (khi == 0)
    out[g] = -0.5f * ss - 14.7030165f + logdet + sumlog;
}

extern "C" void kernel_launch(void* const* d_in, const int* in_sizes, int n_in,
                              void* d_out, int out_size, void* d_ws, size_t ws_size,
                              hipStream_t stream)
{
  const float* x    = (const float*)d_in[0];
  const float* W0   = (const float*)d_in[1];
  const float* b0   = (const float*)d_in[2];
  const float* W1   = (const float*)d_in[3];
  const float* b1   = (const float*)d_in[4];
  const float* W2   = (const float*)d_in[5];
  const float* b2   = (const float*)d_in[6];
  const float* Wout = (const float*)d_in[7];
  const float* bout = (const float*)d_in[8];
  const float* scale= (const float*)d_in[9];
  const float* shift= (const float*)d_in[10];

  int B = in_sizes[0] / 16;

  hipLaunchKernelGGL(prep_kernel, dim3(93), dim3(256), 0, stream,
                     W1, W2, Wout, bout, scale, (char*)d_ws);

  hipLaunchKernelGGL(flow_kernel, dim3(B / 128), dim3(256), LDS_BYTES, stream,
                     x, W0, b0, b1, b2, scale, shift,
                     (const char*)d_ws, (float*)d_out, B);
}

// Round 5
// 195.582 us; speedup vs baseline: 1.9310x; 1.1206x over previous
//
#include <hip/hip_runtime.h>
#include <math.h>

typedef _Float16 f16;
typedef _Float16 half8 __attribute__((ext_vector_type(8)));
typedef float f32x16 __attribute__((ext_vector_type(16)));

#define DEV __device__ __forceinline__

// ---------------- workspace layout (bytes) ----------------
#define W1F_OFF 0        // [L][nt2]      : 16 frags  = 16 KB   (x 2*log2e)
#define W2F_OFF 16384    // [L][kt4][nt2] : 64 frags  = 64 KB   (unscaled)
#define WOF_OFF 81920    // [L][u8][kt4]  : 256 frags = 256 KB  (x log2e)
#define BOF_OFF 344064   // [L][u8][32] fp32 bias (x log2e, +offset folded) = 8 KB
#define SUMLOG_OFF 352256 // 1 fp32: sum over all layers/features of log|scale|
#define W0S_OFF 352320   // [L][16][16] f32 W0 x 2*log2e = 8 KB
#define B0S_OFF 360512   // [L][16]     f32 b0 x 2*log2e = 512 B
#define B1S_OFF 361088   // [L][64]     f32 b1 x 2*log2e = 2 KB (end 363136)

// ---------------- LDS layout (bytes, per block of 256 samples) -------------
// (round-0 proven layout: all strides conflict-free, SQ_LDS_BANK_CONFLICT=0)
#define H0_OFF    0       // [256][48]  : 16 f16/sample
#define H0_STRIDE 48
#define H_OFF     12288   // [256][144] : 64 f16/sample (128+16 pad)
#define H_STRIDE  144
#define P_OFF     49152   // [256][116] : 29 fp32/sample (stride 29 dwords, conflict-free b32)
#define P_STRIDE  116
#define LDS_BYTES 78848

DEV float frcp(float x){ return __builtin_amdgcn_rcpf(x); }

#if __has_builtin(__builtin_amdgcn_exp2f)
DEV float fexp2(float x){ return __builtin_amdgcn_exp2f(x); }
#else
DEV float fexp2(float x){ return exp2f(x); }
#endif
#if __has_builtin(__builtin_amdgcn_logf)
DEV float flog2(float x){ return __builtin_amdgcn_logf(x); }
#else
DEV float flog2(float x){ return log2f(x); }
#endif

#define LN2F    0.69314718056f
#define LOG2EF  1.4426950409f
#define TWOLOG2EF 2.8853900818f

// tanh with PRE-SCALED input: x' = 2*log2e * x_linear.
// tanh = 1 - 2/(2^{x'}+1). Robust without clamp: x->+inf: rcp(inf)=0 -> 1;
// x->-inf: rcp(1)=1 -> -1. 4 instructions (mul folded into weights at prep).
DEV float ftanh2(float x){
  float e = fexp2(x);
  float r = frcp(e + 1.f);
  return fmaf(-2.f, r, 1.f);
}

// Rational-quadratic spline forward + log-det (fp32, per-thread).
// p is in LOG2 DOMAIN: p[0..24] = linear_params * log2e (softplus offset
// already folded into p[16..24] at prep). ew/eh values are identical to the
// e^{u} of the reference. ld_out is returned in LOG2 units (caller scales
// the accumulated sum by ln2 once).
DEV void rq_spline(const float p[25], float xv, float &y_out, float &ld_out)
{
  float ew[8]; float sw = 0.f;
#pragma unroll
  for (int k = 0; k < 8; ++k){ ew[k] = fexp2(p[k]); sw += ew[k]; }
  float rw = frcp(sw) * 19.9992f;           // (RMAX-RMIN) - K*MIN_BIN

  float xpos[9];
  xpos[0] = -10.f;
#pragma unroll
  for (int k = 0; k < 8; ++k) xpos[k + 1] = xpos[k] + fmaf(ew[k], rw, 1e-4f);

  bool b[8];
  int idx = 0;
#pragma unroll
  for (int j = 1; j < 8; ++j){ b[j] = (xv >= xpos[j]); idx += b[j] ? 1 : 0; }

  float xk = xpos[0], ewk = ew[0];
#pragma unroll
  for (int j = 1; j < 8; ++j){
    xk  = b[j] ? xpos[j] : xk;
    ewk = b[j] ? ew[j]   : ewk;
  }
  float bw = fmaf(ewk, rw, 1e-4f);

  float eh[8]; float shs = 0.f;
#pragma unroll
  for (int k = 0; k < 8; ++k){ eh[k] = fexp2(p[8 + k]); shs += eh[k]; }
  float rh = frcp(shs) * 19.9992f;

  float S = 0.f, ehk = eh[0];
#pragma unroll
  for (int k = 1; k < 8; ++k){
    S   += b[k] ? eh[k - 1] : 0.f;
    ehk  = b[k] ? eh[k]     : ehk;
  }
  float yk = fmaf(S, rh, fmaf((float)idx, 1e-4f, -10.f));
  float bh = fmaf(ehk, rh, 1e-4f);

  float vA = p[16], vB = p[17];
#pragma unroll
  for (int j = 1; j < 8; ++j){
    vA = b[j] ? p[16 + j] : vA;
    vB = b[j] ? p[17 + j] : vB;
  }
  // softplus in log2 domain: ln(1+e^u) = ln2*(max(v,0)+log2(1+2^{-|v|})),
  // v = u*log2e (offset pre-folded at prep).
  float tA = fmaxf(vA, 0.f) + flog2(1.f + fexp2(-fabsf(vA)));
  float dk  = fmaf(LN2F, tA, 1e-4f);
  float tB = fmaxf(vB, 0.f) + flog2(1.f + fexp2(-fabsf(vB)));
  float dk1 = fmaf(LN2F, tB, 1e-4f);

  float rbw = frcp(bw);
  float s   = bh * rbw;
  float zf  = fminf(fmaxf((xv - xk) * rbw, 0.f), 1.f);
  float z1  = 1.f - zf;
  float zz  = zf * zf, z01 = zf * z1;
  float den = s + (dk1 + dk - 2.f * s) * z01;
  float rden = frcp(den);
  float yv  = yk + bh * (s * zz + dk * z01) * rden;
  float num = dk1 * zz + 2.f * s * z01 + dk * z1 * z1;
  float ldv2 = flog2(s * s * num * rden * rden);   // log2-domain

  bool outside = (xv <= -10.f) || (xv >= 10.f);
  y_out  = outside ? xv : yv;
  ld_out = outside ? 0.f : ldv2;
}

// ---------------- prep kernel: pack fp16 B-fragments into ws ----------------
// Scaling folded in: W1/b1/W0/b0 x 2*log2e (tanh exp2 path), Wout/bout
// x log2e (+ softplus offset into bout cols 16..24). W2/b2 UNscaled (h2 is
// linear and feeds the Wout MFMA).
extern "C" __global__ void __launch_bounds__(256)
prep_kernel(const float* __restrict__ W0, const float* __restrict__ b0,
            const float* __restrict__ W1, const float* __restrict__ b1,
            const float* __restrict__ W2,
            const float* __restrict__ Wo, const float* __restrict__ bout,
            const float* __restrict__ scale, char* __restrict__ ws)
{
  int tid = blockIdx.x * 256 + threadIdx.x;
  if (tid < 1024){                       // W1 frags: [L][nt2]  (x 2*log2e)
    int fi = tid >> 6, lane = tid & 63;
    int l = fi >> 1, nt = fi & 1;
    int n = nt * 32 + (lane & 31), khi = lane >> 5;
    half8 h;
#pragma unroll
    for (int j = 0; j < 8; ++j){ int k = khi * 8 + j; h[j] = (f16)(W1[l * 1024 + k * 64 + n] * TWOLOG2EF); }
    *(half8*)(ws + W1F_OFF + fi * 1024 + lane * 16) = h;
  } else if (tid < 5120){                // W2 frags: [L][kt4][nt2] (unscaled)
    int idx = tid - 1024;
    int fi = idx >> 6, lane = idx & 63;
    int l = fi >> 3, kt = (fi >> 1) & 3, nt = fi & 1;
    int n = nt * 32 + (lane & 31), khi = lane >> 5;
    half8 h;
#pragma unroll
    for (int j = 0; j < 8; ++j){ int k = kt * 16 + khi * 8 + j; h[j] = (f16)W2[l * 4096 + k * 64 + n]; }
    *(half8*)(ws + W2F_OFF + fi * 1024 + lane * 16) = h;
  } else if (tid < 21504){               // Wout used-col frags: [L][u8][kt4] (x log2e)
    int idx = tid - 5120;
    int fi = idx >> 6, lane = idx & 63;
    int l = fi >> 5, u = (fi >> 2) & 7, kt = fi & 3;
    int f = (l & 1) + 2 * u;
    int c = lane & 31, khi = lane >> 5;
    half8 h;
#pragma unroll
    for (int j = 0; j < 8; ++j){
      int k = kt * 16 + khi * 8 + j;
      float v = (c < 25) ? Wo[l * 25600 + k * 400 + f * 25 + c] * LOG2EF : 0.f;
      h[j] = (f16)v;
    }
    *(half8*)(ws + WOF_OFF + fi * 1024 + lane * 16) = h;
  } else if (tid < 23552){               // bout used cols: [L][u8][32] fp32
    int idx = tid - 21504;
    int l = idx >> 8, u = (idx >> 5) & 7, c = idx & 31;
    int f = (l & 1) + 2 * u;
    float v = 0.f;
    if (c < 25){
      v = bout[l * 400 + f * 25 + c];
      if (c >= 16) v += 0.54116666f;     // softplus offset folded
      v *= LOG2EF;
    }
    ((float*)(ws + BOF_OFF))[idx] = v;
  } else if (tid == 23552){              // sum of log|scale| over all layers
    float acc = 0.f;
    for (int i = 0; i < 128; ++i) acc += logf(fabsf(scale[i]));
    *(float*)(ws + SUMLOG_OFF) = acc;
  } else if (tid < 25601){               // W0 scaled copy: 2048 floats
    int idx = tid - 23553;
    ((float*)(ws + W0S_OFF))[idx] = W0[idx] * TWOLOG2EF;
  } else if (tid < 25729){               // b0 scaled copy: 128 floats
    int idx = tid - 25601;
    ((float*)(ws + B0S_OFF))[idx] = b0[idx] * TWOLOG2EF;
  } else if (tid < 26241){               // b1 scaled copy: 512 floats
    int idx = tid - 25729;
    ((float*)(ws + B1S_OFF))[idx] = b1[idx] * TWOLOG2EF;
  }
}

// ---------------- one coupling layer (all LDS traffic wave-private) --------
// Round-0 proven structure: 64 samples/wave, 1 lane/sample.
// (The 32-samples/wave 2-lane variant measured SLOWER — kernel is
// VALU-throughput-bound, not occupancy-bound; its shfl overhead was net
// negative. Do not re-split.)
template<int PAR>
DEV void layer_mfma(int l,
                    const float* __restrict__ b2v,
                    const float* __restrict__ scv, const float* __restrict__ shv,
                    const char* __restrict__ ws, char* lds,
                    float (&z)[16], float &logdet,
                    int t, int lane, int wv, int ln31, int khi)
{
  const float* w0  = (const float*)(ws + W0S_OFF) + l * 256;   // x 2*log2e
  const float* bb0 = (const float*)(ws + B0S_OFF) + l * 16;    // x 2*log2e
  const int rowbase = khi * 4;     // C/D layout: row = (i&3)+8*(i>>2)+4*(lane>>5)

  // ---- hoisted weight-fragment loads (latency hidden behind h0 VALU) ----
  const half8* W1F = (const half8*)(ws + W1F_OFF);
  const half8* W2F = (const half8*)(ws + W2F_OFF);
  half8 w1f[2];
#pragma unroll
  for (int nt = 0; nt < 2; ++nt) w1f[nt] = W1F[(l * 2 + nt) * 64 + lane];
  half8 w2f[8];
#pragma unroll
  for (int kt = 0; kt < 4; ++kt)
#pragma unroll
    for (int nt = 0; nt < 2; ++nt)
      w2f[kt * 2 + nt] = W2F[((l * 4 + kt) * 2 + nt) * 64 + lane];
  float bias1[2], bias2[2];
#pragma unroll
  for (int nt = 0; nt < 2; ++nt){
    bias1[nt] = ((const float*)(ws + B1S_OFF))[l * 64 + nt * 32 + ln31]; // x 2*log2e
    bias2[nt] = b2v[l * 64 + nt * 32 + ln31];                            // unscaled
  }

  // ---- h0 = tanh(mz @ W0 + b0), per-thread VALU (weights pre-scaled) ----
  float h0[16];
#pragma unroll
  for (int j = 0; j < 16; ++j) h0[j] = bb0[j];
#pragma unroll
  for (int u = 0; u < 8; ++u){
    const int f = (1 - PAR) + 2 * u;
    const float v = z[f];
#pragma unroll
    for (int j = 0; j < 16; ++j) h0[j] = fmaf(v, w0[f * 16 + j], h0[j]);
  }
  {
    half8 lo, hi;
#pragma unroll
    for (int j = 0; j < 8; ++j){ lo[j] = (f16)ftanh2(h0[j]); hi[j] = (f16)ftanh2(h0[8 + j]); }
    *(half8*)(lds + H0_OFF + t * H0_STRIDE)      = lo;
    *(half8*)(lds + H0_OFF + t * H0_STRIDE + 16) = hi;
  }

  // ---- W1: h1 = tanh(h0 @ W1 + b1) via MFMA (bias folded into acc init) ----
  half8 a0[2];
#pragma unroll
  for (int mt = 0; mt < 2; ++mt){
    int s = wv * 64 + mt * 32 + ln31;
    a0[mt] = *(const half8*)(lds + H0_OFF + s * H0_STRIDE + khi * 16);
  }
  f32x16 d1[2][2];
#pragma unroll
  for (int mt = 0; mt < 2; ++mt)
#pragma unroll
    for (int nt = 0; nt < 2; ++nt)
#pragma unroll
      for (int i = 0; i < 16; ++i) d1[mt][nt][i] = bias1[nt];
#pragma unroll
  for (int nt = 0; nt < 2; ++nt)
#pragma unroll
    for (int mt = 0; mt < 2; ++mt)
      d1[mt][nt] = __builtin_amdgcn_mfma_f32_32x32x16_f16(a0[mt], w1f[nt], d1[mt][nt], 0, 0, 0);
#pragma unroll
  for (int mt = 0; mt < 2; ++mt)
#pragma unroll
    for (int nt = 0; nt < 2; ++nt)
#pragma unroll
      for (int i = 0; i < 16; ++i){
        int row = (i & 3) + 8 * (i >> 2) + rowbase;
        int s = wv * 64 + mt * 32 + row;
        float v = ftanh2(d1[mt][nt][i]);
        *(f16*)(lds + H_OFF + s * H_STRIDE + (nt * 32 + ln31) * 2) = (f16)v;
      }

  // ---- W2: h2 = h1 @ W2 + b2 via MFMA (bias folded) ----
  half8 a1[2][4];
#pragma unroll
  for (int mt = 0; mt < 2; ++mt){
    int s = wv * 64 + mt * 32 + ln31;
#pragma unroll
    for (int kt = 0; kt < 4; ++kt)
      a1[mt][kt] = *(const half8*)(lds + H_OFF + s * H_STRIDE + kt * 32 + khi * 16);
  }
  f32x16 d2[2][2];
#pragma unroll
  for (int mt = 0; mt < 2; ++mt)
#pragma unroll
    for (int nt = 0; nt < 2; ++nt)
#pragma unroll
      for (int i = 0; i < 16; ++i) d2[mt][nt][i] = bias2[nt];
#pragma unroll
  for (int kt = 0; kt < 4; ++kt)
#pragma unroll
    for (int nt = 0; nt < 2; ++nt)
#pragma unroll
      for (int mt = 0; mt < 2; ++mt)
        d2[mt][nt] = __builtin_amdgcn_mfma_f32_32x32x16_f16(a1[mt][kt], w2f[kt * 2 + nt], d2[mt][nt], 0, 0, 0);

  // ---- prefetch feature u=0's Wout frags (hidden behind W2 epilogue) ----
  const half8* WOF = (const half8*)(ws + WOF_OFF);
  const float* BOF = (const float*)(ws + BOF_OFF);
  half8 bfn[4];
#pragma unroll
  for (int kt = 0; kt < 4; ++kt) bfn[kt] = WOF[((l * 8 + 0) * 4 + kt) * 64 + lane];
  float biasn = BOF[(l * 8 + 0) * 32 + ln31];

#pragma unroll
  for (int mt = 0; mt < 2; ++mt)
#pragma unroll
    for (int nt = 0; nt < 2; ++nt)
#pragma unroll
      for (int i = 0; i < 16; ++i){
        int row = (i & 3) + 8 * (i >> 2) + rowbase;
        int s = wv * 64 + mt * 32 + row;
        float v = d2[mt][nt][i];
        *(f16*)(lds + H_OFF + s * H_STRIDE + (nt * 32 + ln31) * 2) = (f16)v;
      }

  // ---- h2 A-fragments (reused across all 8 features) ----
  half8 a2[2][4];
#pragma unroll
  for (int mt = 0; mt < 2; ++mt){
    int s = wv * 64 + mt * 32 + ln31;
#pragma unroll
    for (int kt = 0; kt < 4; ++kt)
      a2[mt][kt] = *(const half8*)(lds + H_OFF + s * H_STRIDE + kt * 32 + khi * 16);
  }

  // ---- feature-loop software pipeline ----
  // Stage: p_{u+1} MFMA + LDS-store issued BEFORE spline(u); the spline's
  // long VALU chain hides the entire next-feature LDS round trip. Single
  // p-slot is safe: per-wave DS ops execute in program order, so reads of
  // p_u precede the stores of p_{u+1}.
  {
    f32x16 dp[2];
#pragma unroll
    for (int mt = 0; mt < 2; ++mt)
#pragma unroll
      for (int i = 0; i < 16; ++i) dp[mt][i] = biasn;
#pragma unroll
    for (int kt = 0; kt < 4; ++kt)
#pragma unroll
      for (int mt = 0; mt < 2; ++mt)
        dp[mt] = __builtin_amdgcn_mfma_f32_32x32x16_f16(a2[mt][kt], bfn[kt], dp[mt], 0, 0, 0);
    if (ln31 < 25){
#pragma unroll
      for (int mt = 0; mt < 2; ++mt)
#pragma unroll
        for (int i = 0; i < 16; ++i){
          int row = (i & 3) + 8 * (i >> 2) + rowbase;
          int s = wv * 64 + mt * 32 + row;
          *(float*)(lds + P_OFF + s * P_STRIDE + ln31 * 4) = dp[mt][i];
        }
    }
  }
#pragma unroll
  for (int kt = 0; kt < 4; ++kt) bfn[kt] = WOF[((l * 8 + 1) * 4 + kt) * 64 + lane];
  biasn = BOF[(l * 8 + 1) * 32 + ln31];

#pragma unroll 1
  for (int u = 0; u < 8; ++u){
    // read own sample's p for feature u
    float p[25];
#pragma unroll
    for (int j = 0; j < 25; ++j)
      p[j] = *(const float*)(lds + P_OFF + t * P_STRIDE + j * 4);

    // issue next feature's MFMA + store before the spline
    if (u < 7){
      f32x16 dp[2];
#pragma unroll
      for (int mt = 0; mt < 2; ++mt)
#pragma unroll
        for (int i = 0; i < 16; ++i) dp[mt][i] = biasn;
#pragma unroll
      for (int kt = 0; kt < 4; ++kt)
#pragma unroll
        for (int mt = 0; mt < 2; ++mt)
          dp[mt] = __builtin_amdgcn_mfma_f32_32x32x16_f16(a2[mt][kt], bfn[kt], dp[mt], 0, 0, 0);
      if (ln31 < 25){
#pragma unroll
        for (int mt = 0; mt < 2; ++mt)
#pragma unroll
          for (int i = 0; i < 16; ++i){
            int row = (i & 3) + 8 * (i >> 2) + rowbase;
            int s = wv * 64 + mt * 32 + row;
            *(float*)(lds + P_OFF + s * P_STRIDE + ln31 * 4) = dp[mt][i];
          }
      }
      if (u < 6){
#pragma unroll
        for (int kt = 0; kt < 4; ++kt) bfn[kt] = WOF[((l * 8 + u + 2) * 4 + kt) * 64 + lane];
        biasn = BOF[(l * 8 + u + 2) * 32 + ln31];
      }
    }

    const int f = PAR + 2 * u;
    float y, ld;
    rq_spline(p, z[f], y, ld);
    z[f] = y;
    logdet += ld;                       // log2-domain accumulation
  }

  // ---- affine (log|scale| sum precomputed in prep) ----
  const float* scp = scv + l * 16;
  const float* shp = shv + l * 16;
#pragma unroll
  for (int j = 0; j < 16; ++j)
    z[j] = fmaf(z[j], scp[j], shp[j]);
}

extern "C" __global__ void __launch_bounds__(256, 2)
flow_kernel(const float* __restrict__ x,
            const float* __restrict__ b2v,
            const float* __restrict__ scv, const float* __restrict__ shv,
            const char* __restrict__ ws, float* __restrict__ out, int B)
{
  extern __shared__ char lds[];
  const int t    = threadIdx.x;
  const int lane = t & 63;
  const int wv   = t >> 6;
  const int ln31 = lane & 31;
  const int khi  = lane >> 5;
  const int g    = blockIdx.x * 256 + t;

  float z[16];
  const float4* xv = reinterpret_cast<const float4*>(x + (size_t)g * 16);
  float4 a0 = xv[0], a1 = xv[1], a2 = xv[2], a3 = xv[3];
  z[0]=a0.x; z[1]=a0.y; z[2]=a0.z; z[3]=a0.w;
  z[4]=a1.x; z[5]=a1.y; z[6]=a1.z; z[7]=a1.w;
  z[8]=a2.x; z[9]=a2.y; z[10]=a2.z; z[11]=a2.w;
  z[12]=a3.x; z[13]=a3.y; z[14]=a3.z; z[15]=a3.w;

  float logdet = 0.f;                 // in log2 units
  for (int l = 7; l >= 0; --l){
    if (l & 1) layer_mfma<1>(l, b2v, scv, shv, ws, lds, z, logdet, t, lane, wv, ln31, khi);
    else       layer_mfma<0>(l, b2v, scv, shv, ws, lds, z, logdet, t, lane, wv, ln31, khi);
  }

  float sumlog = *(const float*)(ws + SUMLOG_OFF);
  float ss = 0.f;
#pragma unroll
  for (int j = 0; j < 16; ++j) ss = fmaf(z[j], z[j], ss);
  out[g] = fmaf(LN2F, logdet, -0.5f * ss - 14.7030165f + sumlog);
}

extern "C" void kernel_launch(void* const* d_in, const int* in_sizes, int n_in,
                              void* d_out, int out_size, void* d_ws, size_t ws_size,
                              hipStream_t stream)
{
  const float* x    = (const float*)d_in[0];
  const float* W0   = (const float*)d_in[1];
  const float* b0   = (const float*)d_in[2];
  const float* W1   = (const float*)d_in[3];
  const float* b1   = (const float*)d_in[4];
  const float* W2   = (const float*)d_in[5];
  const float* b2   = (const float*)d_in[6];
  const float* Wout = (const float*)d_in[7];
  const float* bout = (const float*)d_in[8];
  const float* scale= (const float*)d_in[9];
  const float* shift= (const float*)d_in[10];

  int B = in_sizes[0] / 16;

  hipLaunchKernelGGL(prep_kernel, dim3(103), dim3(256), 0, stream,
                     W0, b0, W1, b1, W2, Wout, bout, scale, (char*)d_ws);

  hipLaunchKernelGGL(flow_kernel, dim3(B / 256), dim3(256), LDS_BYTES, stream,
                     x, b2, scale, shift,
                     (const char*)d_ws, (float*)d_out, B);
}